// Round 1
// baseline (470.873 us; speedup 1.0000x reference)
//
#include <hip/hip_runtime.h>

// PrimalDualNetwork: 10-iter Chambolle-Pock ROF on 2048x2048 fp32.
// Strategy R1: 2 kernels/iteration (dual then primal), w recomputed from img
// on the fly (w is constant across iterations), x_tilde lives in d_out,
// x / y_h / y_v in d_ws (48 MB). Scalar fp32 loads, correctness-first.

namespace {
constexpr int M = 2048, N = 2048;
constexpr float SIGMA   = 1.0f / (7.0f * 0.01f);
constexpr float TAU     = 0.01f;
constexpr float THETA   = 0.5f;
constexpr float LT      = 4.0f * 0.01f;              // lambda*tau
constexpr float INV_DEN = 1.0f / (1.0f + 4.0f * 0.01f);
} // namespace

// Dual update: y = clamp(y + SIGMA * w * forward_grad(x_tilde), -1, 1)
// first==1: x_tilde == img, and y_old = forward_grad(img) computed in-place.
__global__ __launch_bounds__(256) void dual_k(const float* __restrict__ xt,
                                              const float* __restrict__ img,
                                              float* __restrict__ yh,
                                              float* __restrict__ yv,
                                              const float* __restrict__ w1p,
                                              const float* __restrict__ w2p,
                                              int first)
{
    int idx = blockIdx.x * 256 + threadIdx.x;
    int i = idx >> 11;          // N == 2048
    int j = idx & (N - 1);
    float w1 = w1p[0], w2 = w2p[0];

    float c  = xt[idx];
    bool jn  = (j < N - 1);
    bool in_ = (i < M - 1);
    float gh = jn  ? xt[idx + 1] - c : 0.0f;   // forward diff, 0 at last col
    float gv = in_ ? xt[idx + N] - c : 0.0f;   // forward diff, 0 at last row

    float gh0, gv0;
    if (first) {               // x_tilde == img: grad(img) == grad(x_tilde)
        gh0 = gh; gv0 = gv;
    } else {
        float ic = img[idx];
        gh0 = jn  ? img[idx + 1] - ic : 0.0f;
        gv0 = in_ ? img[idx + N] - ic : 0.0f;
    }
    float wh = w1 + w2 * __expf(-fabsf(gh0));
    float wv = w1 + w2 * __expf(-fabsf(gv0));

    float yho = first ? gh0 : yh[idx];   // y init = forward_grad(img)
    float yvo = first ? gv0 : yv[idx];

    float nh = yho + SIGMA * wh * gh;
    float nv = yvo + SIGMA * wv * gv;
    yh[idx] = fminf(fmaxf(nh, -1.0f), 1.0f);
    yv[idx] = fminf(fmaxf(nv, -1.0f), 1.0f);
}

// Primal update:
//   x_new   = (x + TAU * div(w*y) + LT * img) / (1 + LT)
//   x_tilde = x_new + THETA * (x_new - x)
// div(p)[i,j] = p_h[i,j] - p_h[i,j-1] + p_v[i,j] - p_v[i-1,j]
// (zero-padded left/top; exact because y_h[:,N-1] == y_v[M-1,:] == 0 always)
__global__ __launch_bounds__(256) void primal_k(const float* __restrict__ yh,
                                                const float* __restrict__ yv,
                                                const float* __restrict__ img,
                                                float* __restrict__ x,
                                                float* __restrict__ xt,
                                                const float* __restrict__ w1p,
                                                const float* __restrict__ w2p,
                                                int first)
{
    int idx = blockIdx.x * 256 + threadIdx.x;
    int i = idx >> 11;
    int j = idx & (N - 1);
    float w1 = w1p[0], w2 = w2p[0];

    float ic = img[idx];

    float ph, pv, phm = 0.0f, pvm = 0.0f;
    {
        float g  = (j < N - 1) ? img[idx + 1] - ic : 0.0f;
        float wh = w1 + w2 * __expf(-fabsf(g));
        ph = wh * yh[idx];
    }
    {
        float g  = (i < M - 1) ? img[idx + N] - ic : 0.0f;
        float wv = w1 + w2 * __expf(-fabsf(g));
        pv = wv * yv[idx];
    }
    if (j > 0) {
        float g  = ic - img[idx - 1];           // gh0 at (i, j-1)
        float wh = w1 + w2 * __expf(-fabsf(g));
        phm = wh * yh[idx - 1];
    }
    if (i > 0) {
        float g  = ic - img[idx - N];           // gv0 at (i-1, j)
        float wv = w1 + w2 * __expf(-fabsf(g));
        pvm = wv * yv[idx - N];
    }

    float div = (ph - phm) + (pv - pvm);
    float xo  = first ? ic : x[idx];
    float xn  = (xo + TAU * div + LT * ic) * INV_DEN;
    x[idx]  = xn;
    xt[idx] = xn + THETA * (xn - xo);
}

extern "C" void kernel_launch(void* const* d_in, const int* in_sizes, int n_in,
                              void* d_out, int out_size, void* d_ws, size_t ws_size,
                              hipStream_t stream)
{
    const float* img = (const float*)d_in[0];
    const float* w1  = (const float*)d_in[1];
    const float* w2  = (const float*)d_in[2];

    float* xt = (float*)d_out;                       // x_tilde lives in d_out
    char*  ws = (char*)d_ws;
    const size_t PLANE = (size_t)M * N * sizeof(float);
    float* x  = (float*)(ws);
    float* yh = (float*)(ws + PLANE);
    float* yv = (float*)(ws + 2 * PLANE);

    const int nthreads = 256;
    const int nblocks  = (M * N) / nthreads;

    // Iteration 0: x_tilde == img, y seeded from grad(img) inside dual_k.
    dual_k<<<nblocks, nthreads, 0, stream>>>(img, img, yh, yv, w1, w2, 1);
    primal_k<<<nblocks, nthreads, 0, stream>>>(yh, yv, img, x, xt, w1, w2, 1);

    for (int it = 1; it < 10; ++it) {
        dual_k<<<nblocks, nthreads, 0, stream>>>(xt, img, yh, yv, w1, w2, 0);
        primal_k<<<nblocks, nthreads, 0, stream>>>(yh, yv, img, x, xt, w1, w2, 0);
    }
}

// Round 2
// 343.014 us; speedup vs baseline: 1.3728x; 1.3728x over previous
//
#include <hip/hip_runtime.h>

// PrimalDualNetwork: 10-iter Chambolle-Pock ROF on 2048x2048 fp32.
// R2: fused dual+primal per iteration (10 launches), float4 everywhere,
// w recomputed from img on the fly (constant across iterations).
// Block computes dual on tile + top/left halo into LDS (w*y), then primal
// from LDS. xt and y ping-pong across iterations (cross-block halo reads
// must see the PREVIOUS iteration's values).

namespace {
constexpr int M = 2048, N = 2048;
constexpr float SIGMA   = 1.0f / (7.0f * 0.01f);
constexpr float TAU     = 0.01f;
constexpr float LT      = 4.0f * 0.01f;              // lambda*tau
constexpr float INV_DEN = 1.0f / (1.0f + 4.0f * 0.01f);
constexpr int TW = 128, TH = 32;   // tile cols x rows per block (256 threads)
constexpr int LP = 132;            // LDS pitch (floats); col 128 = left-halo col
constexpr int GX = N / TW;         // 16
constexpr int GY = M / TH;         // 64
} // namespace

__global__ __launch_bounds__(256) void fused_k(
    const float* __restrict__ xt_r, float* __restrict__ xt_w,
    const float* __restrict__ yh_r, const float* __restrict__ yv_r,
    float* __restrict__ yh_w, float* __restrict__ yv_w,
    const float* __restrict__ img, float* __restrict__ x,
    const float* __restrict__ w1p, const float* __restrict__ w2p,
    int first)
{
    __shared__ float s_wyh[(TH + 1) * LP];   // rows 0..32 <-> gi = r0-1+ri
    __shared__ float s_wyv[(TH + 1) * LP];   // col 128 <-> gj = c0-1

    const int tid = threadIdx.x;
    const int c0 = blockIdx.x * TW;
    const int r0 = blockIdx.y * TH;
    const float w1 = w1p[0], w2 = w2p[0];

    // ---------- Phase 1: dual on rows r0-1..r0+TH-1, cols c0..c0+TW-1 ----------
    for (int k = 0; k < 5; ++k) {
        int item = k * 256 + tid;
        if (item < (TH + 1) * 32) {
            int ri  = item >> 5;           // 0..32
            int cc  = (item & 31) << 2;    // LDS col base 0..124
            int gi  = r0 - 1 + ri;
            int gj  = c0 + cc;
            int lb  = ri * LP + cc;
            if (gi < 0) {
                *(float4*)(s_wyh + lb) = make_float4(0.f, 0.f, 0.f, 0.f);
                *(float4*)(s_wyv + lb) = make_float4(0.f, 0.f, 0.f, 0.f);
            } else {
                size_t idx = (size_t)gi * N + gj;
                const bool has_r = (gj + 4 < N);       // lane3 has a right neighbor
                const bool has_d = (gi < M - 1);

                float4 c4 = *(const float4*)(xt_r + idx);
                float  cR = has_r ? xt_r[idx + 4] : 0.f;
                float4 d4 = has_d ? *(const float4*)(xt_r + idx + N)
                                  : make_float4(0.f, 0.f, 0.f, 0.f);
                float4 i4; float iR; float4 b4;
                if (first) { i4 = c4; iR = cR; b4 = d4; }
                else {
                    i4 = *(const float4*)(img + idx);
                    iR = has_r ? img[idx + 4] : 0.f;
                    b4 = has_d ? *(const float4*)(img + idx + N)
                               : make_float4(0.f, 0.f, 0.f, 0.f);
                }

                float ca[4]  = {c4.x, c4.y, c4.z, c4.w};
                float da[4]  = {d4.x, d4.y, d4.z, d4.w};
                float ia[4]  = {i4.x, i4.y, i4.z, i4.w};
                float ba[4]  = {b4.x, b4.y, b4.z, b4.w};

                float gh[4], gv[4], g0h[4], g0v[4];
                gh[0] = ca[1] - ca[0]; gh[1] = ca[2] - ca[1]; gh[2] = ca[3] - ca[2];
                gh[3] = has_r ? (cR - ca[3]) : 0.f;
                g0h[0] = ia[1] - ia[0]; g0h[1] = ia[2] - ia[1]; g0h[2] = ia[3] - ia[2];
                g0h[3] = has_r ? (iR - ia[3]) : 0.f;
                #pragma unroll
                for (int l = 0; l < 4; ++l) {
                    gv[l]  = has_d ? (da[l] - ca[l]) : 0.f;
                    g0v[l] = has_d ? (ba[l] - ia[l]) : 0.f;
                }

                float yho[4], yvo[4];
                if (first) {
                    #pragma unroll
                    for (int l = 0; l < 4; ++l) { yho[l] = g0h[l]; yvo[l] = g0v[l]; }
                } else {
                    float4 t = *(const float4*)(yh_r + idx);
                    yho[0] = t.x; yho[1] = t.y; yho[2] = t.z; yho[3] = t.w;
                    float4 u = *(const float4*)(yv_r + idx);
                    yvo[0] = u.x; yvo[1] = u.y; yvo[2] = u.z; yvo[3] = u.w;
                }

                float ynh[4], ynv[4], wyh4[4], wyv4[4];
                #pragma unroll
                for (int l = 0; l < 4; ++l) {
                    float wh = w1 + w2 * __expf(-fabsf(g0h[l]));
                    float wv = w1 + w2 * __expf(-fabsf(g0v[l]));
                    float th = yho[l] + SIGMA * wh * gh[l];
                    float tv = yvo[l] + SIGMA * wv * gv[l];
                    th = fminf(fmaxf(th, -1.f), 1.f);
                    tv = fminf(fmaxf(tv, -1.f), 1.f);
                    ynh[l] = th; ynv[l] = tv;
                    wyh4[l] = wh * th; wyv4[l] = wv * tv;
                }
                *(float4*)(s_wyh + lb) = make_float4(wyh4[0], wyh4[1], wyh4[2], wyh4[3]);
                *(float4*)(s_wyv + lb) = make_float4(wyv4[0], wyv4[1], wyv4[2], wyv4[3]);
                if (ri >= 1) {   // owned rows only (ri==0 is the block above's row)
                    *(float4*)(yh_w + idx) = make_float4(ynh[0], ynh[1], ynh[2], ynh[3]);
                    *(float4*)(yv_w + idx) = make_float4(ynv[0], ynv[1], ynv[2], ynv[3]);
                }
            }
        }
    }

    // ---------- Phase 1b: left-halo col gj = c0-1, rows r0-1..r0+TH-1 ----------
    if (tid < TH + 1) {
        int ri = tid;
        int gi = r0 - 1 + ri;
        int gj = c0 - 1;
        int lb = ri * LP + 128;
        float wyhv = 0.f, wyvv = 0.f;
        if (gi >= 0 && gj >= 0) {
            size_t idx = (size_t)gi * N + gj;
            bool has_d = (gi < M - 1);
            float c = xt_r[idx];
            float r = xt_r[idx + 1];                     // gj+1 = c0 < N always
            float d = has_d ? xt_r[idx + N] : 0.f;
            float ic, ir, ib;
            if (first) { ic = c; ir = r; ib = d; }
            else {
                ic = img[idx]; ir = img[idx + 1];
                ib = has_d ? img[idx + N] : 0.f;
            }
            float gh  = r - c;
            float gv  = has_d ? (d - c) : 0.f;
            float g0h = ir - ic;
            float g0v = has_d ? (ib - ic) : 0.f;
            float yho, yvo;
            if (first) { yho = g0h; yvo = g0v; }
            else { yho = yh_r[idx]; yvo = yv_r[idx]; }
            float wh = w1 + w2 * __expf(-fabsf(g0h));
            float wv = w1 + w2 * __expf(-fabsf(g0v));
            float th = fminf(fmaxf(yho + SIGMA * wh * gh, -1.f), 1.f);
            float tv = fminf(fmaxf(yvo + SIGMA * wv * gv, -1.f), 1.f);
            wyhv = wh * th; wyvv = wv * tv;
            // no global write: this column is owned by the left block
        }
        s_wyh[lb] = wyhv;
        s_wyv[lb] = wyvv;
    }

    __syncthreads();

    // ---------- Phase 2: primal on tile rows r0..r0+TH-1, cols c0..c0+TW-1 ----------
    for (int k = 0; k < 4; ++k) {
        int item = k * 256 + tid;
        int pr  = item >> 5;            // 0..31
        int cc  = (item & 31) << 2;     // 0..124
        int gi  = r0 + pr;
        int gj  = c0 + cc;
        int ri  = pr + 1;               // LDS row
        size_t idx = (size_t)gi * N + gj;

        float4 h4 = *(const float4*)(s_wyh + ri * LP + cc);
        float  hm = (cc == 0) ? s_wyh[ri * LP + 128] : s_wyh[ri * LP + cc - 1];
        float4 v4 = *(const float4*)(s_wyv + ri * LP + cc);
        float4 u4 = *(const float4*)(s_wyv + (ri - 1) * LP + cc);

        float4 ii = *(const float4*)(img + idx);
        float4 xo = first ? ii : *(const float4*)(x + idx);

        float dh[4];
        dh[0] = h4.x - hm;   dh[1] = h4.y - h4.x;
        dh[2] = h4.z - h4.y; dh[3] = h4.w - h4.z;
        float dv[4] = {v4.x - u4.x, v4.y - u4.y, v4.z - u4.z, v4.w - u4.w};
        float xoa[4] = {xo.x, xo.y, xo.z, xo.w};
        float iia[4] = {ii.x, ii.y, ii.z, ii.w};

        float xn[4], xtv[4];
        #pragma unroll
        for (int l = 0; l < 4; ++l) {
            float v = (xoa[l] + TAU * (dh[l] + dv[l]) + LT * iia[l]) * INV_DEN;
            xn[l]  = v;
            xtv[l] = v + 0.5f * (v - xoa[l]);   // THETA = 0.5
        }
        *(float4*)(x + idx)    = make_float4(xn[0], xn[1], xn[2], xn[3]);
        *(float4*)(xt_w + idx) = make_float4(xtv[0], xtv[1], xtv[2], xtv[3]);
    }
}

extern "C" void kernel_launch(void* const* d_in, const int* in_sizes, int n_in,
                              void* d_out, int out_size, void* d_ws, size_t ws_size,
                              hipStream_t stream)
{
    const float* img = (const float*)d_in[0];
    const float* w1  = (const float*)d_in[1];
    const float* w2  = (const float*)d_in[2];

    const size_t P = (size_t)M * N;          // elements per plane
    float* ws  = (float*)d_ws;
    float* x   = ws;                          // primal state (in-place)
    float* yh0 = ws + 1 * P;                  // y ping-pong buffers
    float* yv0 = ws + 2 * P;
    float* yh1 = ws + 3 * P;
    float* yv1 = ws + 4 * P;
    float* xt0 = ws + 5 * P;                  // xt ping-pong: buf0 = ws, buf1 = d_out
    float* xt1 = (float*)d_out;               // iters 1,3,5,7,9 write d_out; final = iter 9

    dim3 grid(GX, GY), block(256);

    for (int it = 0; it < 10; ++it) {
        int p  = it & 1;
        int pp = (it - 1) & 1;
        const float* xtr = (it == 0) ? img : (pp == 0 ? xt0 : xt1);
        float*       xtw = (p == 0) ? xt0 : xt1;
        const float* yhr = (it == 0) ? img : (pp == 0 ? yh0 : yh1);  // unused when first
        const float* yvr = (it == 0) ? img : (pp == 0 ? yv0 : yv1);
        float*       yhw = (p == 0) ? yh0 : yh1;
        float*       yvw = (p == 0) ? yv0 : yv1;
        fused_k<<<grid, block, 0, stream>>>(xtr, xtw, yhr, yvr, yhw, yvw,
                                            img, x, w1, w2, it == 0 ? 1 : 0);
    }
}

// Round 3
// 195.018 us; speedup vs baseline: 2.4145x; 1.7589x over previous
//
#include <hip/hip_runtime.h>
#include <hip/hip_fp16.h>

// PrimalDualNetwork: 10-iter Chambolle-Pock ROF on 2048x2048 fp32.
// R3: FULL fusion — one kernel, all 10 iterations LDS-resident.
// Each block: 64x32 output tile + 10-pixel dependency halo (cone grows 1
// px/iter: dual=forward diff, primal=backward diff). Plane = 52 rows x 92
// pitch, global origin (r0-10, c0-12) (left halo 12 for 16B alignment).
// xt fp32 in LDS; y/w fp16 (y clamps to exact ±1; w in [0.5,0.9]).
// No cone predication: out-of-cone pixels compute finite garbage never read
// by in-cone math (y clamped, x contractive => no Inf/NaN). Only image-
// boundary masks (forward diff zero at last col/row; div zero pad at first).
// HBM traffic: read img (~39MB incl. halo overlap), write xt(9) (16MB).

namespace {
constexpr int M = 2048, N = 2048;
constexpr float SIGMA   = 1.0f / (7.0f * 0.01f);
constexpr float TAU     = 0.01f;
constexpr float LT      = 4.0f * 0.01f;
constexpr float INV_DEN = 1.0f / (1.0f + 4.0f * 0.01f);
constexpr int TW = 64, TH = 32;     // output tile
constexpr int PC = 92;              // plane pitch (elements)
constexpr int PR = 52;              // plane rows: global r0-10 .. r0+41
constexpr int UPR = 22;             // float4-units per row (cols 0..87)
constexpr int PROC_ROWS = 51;       // rows 0..50 processed (row 51 read-only)
constexpr int NU = PROC_ROWS * UPR; // 1122 units
constexpr int NT = 1024;            // threads (16 waves)
} // namespace

typedef __attribute__((ext_vector_type(4))) _Float16 half4;

__global__ __launch_bounds__(NT) void pd_fused(
    const float* __restrict__ img, float* __restrict__ out,
    const float* __restrict__ w1p, const float* __restrict__ w2p)
{
    __shared__ __align__(16) float    sXT[PR * PC];
    __shared__ __align__(16) _Float16 sYH[PR * PC];
    __shared__ __align__(16) _Float16 sYV[PR * PC];
    __shared__ __align__(16) _Float16 sWH[PR * PC];
    __shared__ __align__(16) _Float16 sWV[PR * PC];

    const int tid = threadIdx.x;
    const int c0 = blockIdx.x * TW;
    const int r0 = blockIdx.y * TH;
    const int gr0 = r0 - 10, gc0 = c0 - 12;
    const float w1 = w1p[0], w2 = w2p[0];

    // ---- stage img into sXT (entire plane incl. pad; 0 outside image) ----
    for (int i = tid; i < PR * PC; i += NT) {
        int li = i / PC, lj = i - li * PC;
        int gi = gr0 + li, gj = gc0 + lj;
        float v = 0.f;
        if ((unsigned)gi < (unsigned)M && (unsigned)gj < (unsigned)N)
            v = img[gi * N + gj];
        sXT[i] = v;
    }
    __syncthreads();

    float xreg[2][4], xim[2][4];

    // ---- init: w planes + y(0) (fused t=0 dual: y0 = clamp(g*(1+sigma*w)))
    for (int ui = 0; ui < 2; ++ui) {
        int u = tid + ui * NT;
        if (u < NU) {
            int li  = u / UPR;
            int lj4 = (u - li * UPR) * 4;
            int b   = li * PC + lj4;
            int gi  = gr0 + li;
            int gjb = gc0 + lj4;
            float4 c  = *(const float4*)&sXT[b];
            float4 rr = *(const float4*)&sXT[b + 4];
            float4 d  = *(const float4*)&sXT[b + PC];
            float ca[4] = {c.x, c.y, c.z, c.w};
            float da[4] = {d.x, d.y, d.z, d.w};
            bool vok = (gi < M - 1);
            half4 wh4, wv4, yh4, yv4;
            #pragma unroll
            for (int l = 0; l < 4; ++l) {
                float nxt = (l < 3) ? ca[l + 1] : rr.x;
                float gh = (gjb + l < N - 1) ? (nxt - ca[l]) : 0.f;
                float gv = vok ? (da[l] - ca[l]) : 0.f;
                float wh = fmaf(w2, __expf(-fabsf(gh)), w1);
                float wv = fmaf(w2, __expf(-fabsf(gv)), w1);
                float yh = gh * fmaf(SIGMA, wh, 1.f);
                float yv = gv * fmaf(SIGMA, wv, 1.f);
                yh = fminf(fmaxf(yh, -1.f), 1.f);
                yv = fminf(fmaxf(yv, -1.f), 1.f);
                wh4[l] = (_Float16)wh; wv4[l] = (_Float16)wv;
                yh4[l] = (_Float16)yh; yv4[l] = (_Float16)yv;
                xreg[ui][l] = ca[l];
                xim[ui][l]  = ca[l];
            }
            *(half4*)&sWH[b] = wh4; *(half4*)&sWV[b] = wv4;
            *(half4*)&sYH[b] = yh4; *(half4*)&sYV[b] = yv4;
        }
    }
    __syncthreads();

    #pragma unroll 1
    for (int t = 0; t < 10; ++t) {
        if (t > 0) {
            // ---- dual: y = clamp(y + SIGMA*w*grad(xt)) (in place) ----
            for (int ui = 0; ui < 2; ++ui) {
                int u = tid + ui * NT;
                if (u < NU) {
                    int li  = u / UPR;
                    int lj4 = (u - li * UPR) * 4;
                    int b   = li * PC + lj4;
                    int gi  = gr0 + li;
                    int gjb = gc0 + lj4;
                    float4 c  = *(const float4*)&sXT[b];
                    float4 rr = *(const float4*)&sXT[b + 4];
                    float4 d  = *(const float4*)&sXT[b + PC];
                    half4 yh4 = *(half4*)&sYH[b];
                    half4 yv4 = *(half4*)&sYV[b];
                    half4 wh4 = *(half4*)&sWH[b];
                    half4 wv4 = *(half4*)&sWV[b];
                    float ca[4] = {c.x, c.y, c.z, c.w};
                    float da[4] = {d.x, d.y, d.z, d.w};
                    bool vok = (gi < M - 1);
                    half4 nyh, nyv;
                    #pragma unroll
                    for (int l = 0; l < 4; ++l) {
                        float nxt = (l < 3) ? ca[l + 1] : rr.x;
                        float gh = (gjb + l < N - 1) ? (nxt - ca[l]) : 0.f;
                        float gv = vok ? (da[l] - ca[l]) : 0.f;
                        float yh = fmaf(SIGMA * (float)wh4[l], gh, (float)yh4[l]);
                        float yv = fmaf(SIGMA * (float)wv4[l], gv, (float)yv4[l]);
                        nyh[l] = (_Float16)fminf(fmaxf(yh, -1.f), 1.f);
                        nyv[l] = (_Float16)fminf(fmaxf(yv, -1.f), 1.f);
                    }
                    *(half4*)&sYH[b] = nyh;
                    *(half4*)&sYV[b] = nyv;
                }
            }
            __syncthreads();
        }
        // ---- primal: x = (x + TAU*div(w*y) + LT*img)/(1+LT); xt = 1.5x-0.5xo
        for (int ui = 0; ui < 2; ++ui) {
            int u = tid + ui * NT;
            if (u < NU) {
                int li  = u / UPR;
                int lj4 = (u - li * UPR) * 4;
                int b   = li * PC + lj4;
                int gi  = gr0 + li;
                int gjb = gc0 + lj4;
                int bl = (lj4 > 0) ? b - 4  : b;   // left unit (clamped; only
                int bu = (li  > 0) ? b - PC : b;   // garbage lanes hit clamp)
                half4 yh4 = *(half4*)&sYH[b];
                half4 yhl = *(half4*)&sYH[bl];
                half4 yv4 = *(half4*)&sYV[b];
                half4 yvu = *(half4*)&sYV[bu];
                half4 wh4 = *(half4*)&sWH[b];
                half4 whl = *(half4*)&sWH[bl];
                half4 wv4 = *(half4*)&sWV[b];
                half4 wvu = *(half4*)&sWV[bu];
                bool iok = (gi >= 1);
                float4 xt4;
                float xtv[4];
                #pragma unroll
                for (int l = 0; l < 4; ++l) {
                    float p_h = (float)wh4[l] * (float)yh4[l];
                    float p_hm;
                    if (l == 0) p_hm = (gjb >= 1) ? (float)whl[3] * (float)yhl[3] : 0.f;
                    else        p_hm = (float)wh4[l - 1] * (float)yh4[l - 1];
                    float p_v  = (float)wv4[l] * (float)yv4[l];
                    float p_vm = iok ? (float)wvu[l] * (float)yvu[l] : 0.f;
                    float dvg = (p_h - p_hm) + (p_v - p_vm);
                    float xo = xreg[ui][l];
                    float xn = (fmaf(TAU, dvg, xo) + LT * xim[ui][l]) * INV_DEN;
                    xreg[ui][l] = xn;
                    xtv[l] = fmaf(1.5f, xn, -0.5f * xo);   // THETA = 0.5
                }
                xt4.x = xtv[0]; xt4.y = xtv[1]; xt4.z = xtv[2]; xt4.w = xtv[3];
                *(float4*)&sXT[b] = xt4;
            }
        }
        __syncthreads();
    }

    // ---- output: xt(9) on the 32x64 tile ----
    if (tid < TH * (TW / 4)) {
        int row = tid >> 4;          // 0..31
        int c4  = tid & 15;          // 0..15
        int li = 10 + row, lj = 12 + 4 * c4;
        float4 v = *(const float4*)&sXT[li * PC + lj];
        *(float4*)&out[(size_t)(r0 + row) * N + (c0 + 4 * c4)] = v;
    }
}

extern "C" void kernel_launch(void* const* d_in, const int* in_sizes, int n_in,
                              void* d_out, int out_size, void* d_ws, size_t ws_size,
                              hipStream_t stream)
{
    const float* img = (const float*)d_in[0];
    const float* w1  = (const float*)d_in[1];
    const float* w2  = (const float*)d_in[2];
    float* out = (float*)d_out;

    dim3 grid(N / TW, M / TH);   // 32 x 64 = 2048 blocks
    pd_fused<<<grid, NT, 0, stream>>>(img, out, w1, w2);
}

// Round 4
// 136.487 us; speedup vs baseline: 3.4499x; 1.4288x over previous
//
#include <hip/hip_runtime.h>

// PrimalDualNetwork: 10-iter Chambolle-Pock ROF on 2048x2048 fp32.
// R4: fully-fused single kernel, register-resident dual state.
//  - 64x64 output tile + 10-px dependency halo: plane 84 rows x 88 cols,
//    origin (r0-10, c0-12). Units = float4 groups; UPR=22 covers the WHOLE
//    row => lane->address mapping is fully contiguous => zero LDS bank
//    conflicts (R3 had 2.1e7 conflict cycles from partial-row coverage).
//  - Registers per unit: x, img, xt (fp32x4), y, sigma*w (boundary masks
//    folded in => no per-iter masking), p=w*y (packed _Float16x4, v_pk math).
//  - LDS only for cross-lane needs: sXT (fp32, down-neighbor reads),
//    sPH/sPV (fp16, up/left-neighbor reads). Left/right neighbors within a
//    wave via __shfl (mapping is contiguous); wave-edge lanes use 1-lane
//    predicated LDS reads.
//  - Out-of-cone pixels compute bounded garbage never read in-cone
//    (y clamped, x contractive; cone shrinks 1px/iter monotonically).

namespace {
constexpr int M = 2048, N = 2048;
constexpr float SIGMA     = 1.0f / (7.0f * 0.01f);
constexpr float INV_SIGMA = 7.0f * 0.01f;
constexpr float TAU       = 0.01f;
constexpr float LT        = 4.0f * 0.01f;
constexpr float INV_DEN   = 1.0f / (1.0f + 4.0f * 0.01f);
constexpr int TW = 64, TH = 64;     // output tile
constexpr int PC = 88;              // plane cols (12 left + 64 + 12 right)
constexpr int PR = 84;              // plane rows (10 + 64 + 10)
constexpr int UPR = 22;             // float4 units per row == PC/4 (full cover!)
constexpr int PROC = 83;            // processed rows 0..82 (row 83 read-only)
constexpr int NU = PROC * UPR;      // 1826
constexpr int NT = 1024;            // 16 waves
constexpr int NPASS = 2;
} // namespace

typedef _Float16 h4 __attribute__((ext_vector_type(4)));

__device__ inline h4 h4splat(float v) {
    _Float16 s = (_Float16)v;
    return (h4){s, s, s, s};
}

__global__ __launch_bounds__(NT, 4) void pd_fused(
    const float* __restrict__ img, float* __restrict__ out,
    const float* __restrict__ w1p, const float* __restrict__ w2p)
{
    __shared__ __align__(16) float    sXT[PR * PC];   // 29568 B
    __shared__ __align__(16) _Float16 sPH[PR * PC];   // 14784 B
    __shared__ __align__(16) _Float16 sPV[PR * PC];   // 14784 B

    const int tid  = threadIdx.x;
    const int lane = tid & 63;
    const int c0 = blockIdx.x * TW, r0 = blockIdx.y * TH;
    const int gr0 = r0 - 10, gc0 = c0 - 12;
    const float w1 = w1p[0], w2 = w2p[0];

    // per-pass invariants
    int bF_[NPASS], u_[NPASS], gi_[NPASS], gjb_[NPASS];
    bool act_[NPASS];
    #pragma unroll
    for (int p = 0; p < NPASS; ++p) {
        int u = tid + p * NT;
        int li = u / UPR;
        int uj = u - li * UPR;
        u_[p] = u; act_[p] = (u < NU);
        bF_[p] = u * 4;                 // element index (floats or halves)
        gi_[p] = gr0 + li; gjb_[p] = gc0 + uj * 4;
    }

    // ---- stage img -> sXT (full plane, rows 0..83; 0 outside image) ----
    #pragma unroll
    for (int p = 0; p < NPASS; ++p) {
        int su = tid + p * NT;
        if (su < PR * UPR) {
            int li = su / UPR, uj = su - li * UPR;
            int gi = gr0 + li, gj = gc0 + uj * 4;
            float4 v = make_float4(0.f, 0.f, 0.f, 0.f);
            if ((unsigned)gi < (unsigned)M && (unsigned)gj <= (unsigned)(N - 4))
                v = *(const float4*)&img[(size_t)gi * N + gj];
            *(float4*)&sXT[su * 4] = v;
        }
    }
    __syncthreads();

    // register state
    float xr[NPASS][4], xi[NPASS][4], xt[NPASS][4];
    h4 yh[NPASS], yv[NPASS], swh[NPASS], swv[NPASS], pH[NPASS], pV[NPASS];

    // ---- init: w (masked sigma*w), y(0)=clamp(g0*(1+sigma*w)), p(0)=w*y(0)
    #pragma unroll
    for (int p = 0; p < NPASS; ++p) {
        bool a = act_[p]; int bF = bF_[p];
        float4 c = a ? *(const float4*)&sXT[bF] : make_float4(0.f, 0.f, 0.f, 0.f);
        float rr = __shfl_down(c.x, 1, 64);
        if (lane == 63 && a) rr = sXT[bF + 4];
        float4 d = a ? *(const float4*)&sXT[bF + PC] : make_float4(0.f, 0.f, 0.f, 0.f);
        float ca[4] = {c.x, c.y, c.z, c.w};
        float da[4] = {d.x, d.y, d.z, d.w};
        bool vok = gi_[p] < M - 1;
        #pragma unroll
        for (int l = 0; l < 4; ++l) {
            float nxt = (l < 3) ? ca[l + 1] : rr;
            bool hok = (gjb_[p] + l) < N - 1;
            float gh = hok ? nxt - ca[l] : 0.f;
            float gv = vok ? da[l] - ca[l] : 0.f;
            float wh = fmaf(w2, __expf(-fabsf(gh)), w1);
            float wv = fmaf(w2, __expf(-fabsf(gv)), w1);
            float y0h = fminf(fmaxf(gh * fmaf(SIGMA, wh, 1.f), -1.f), 1.f);
            float y0v = fminf(fmaxf(gv * fmaf(SIGMA, wv, 1.f), -1.f), 1.f);
            yh[p][l]  = (_Float16)y0h;            yv[p][l]  = (_Float16)y0v;
            swh[p][l] = (_Float16)(hok ? SIGMA * wh : 0.f);
            swv[p][l] = (_Float16)(vok ? SIGMA * wv : 0.f);
            pH[p][l]  = (_Float16)(wh * y0h);     pV[p][l]  = (_Float16)(wv * y0v);
            xr[p][l] = ca[l]; xi[p][l] = ca[l]; xt[p][l] = ca[l];
        }
        if (a) { *(h4*)&sPH[bF] = pH[p]; *(h4*)&sPV[bF] = pV[p]; }
    }
    __syncthreads();

    // ---- dual (t>=1): y += sw*grad(xt), clamp; p = (sw*y)/sigma ----
    auto dual = [&]() {
        #pragma unroll
        for (int p = 0; p < NPASS; ++p) {
            bool a = act_[p]; int bF = bF_[p];
            float rr = __shfl_down(xt[p][0], 1, 64);
            if (lane == 63 && a) rr = sXT[bF + 4];
            float4 d = a ? *(const float4*)&sXT[bF + PC] : make_float4(0.f, 0.f, 0.f, 0.f);
            float da[4] = {d.x, d.y, d.z, d.w};
            h4 ghh, gvh;
            #pragma unroll
            for (int l = 0; l < 4; ++l) {
                float nxt = (l < 3) ? xt[p][l + 1] : rr;
                ghh[l] = (_Float16)(nxt - xt[p][l]);
                gvh[l] = (_Float16)(da[l] - xt[p][l]);
            }
            h4 nh = yh[p] + swh[p] * ghh;     // masked sw => border y stays 0
            h4 nv = yv[p] + swv[p] * gvh;
            nh = __builtin_elementwise_min(__builtin_elementwise_max(nh, h4splat(-1.f)), h4splat(1.f));
            nv = __builtin_elementwise_min(__builtin_elementwise_max(nv, h4splat(-1.f)), h4splat(1.f));
            yh[p] = nh; yv[p] = nv;
            h4 is = h4splat(INV_SIGMA);
            pH[p] = (swh[p] * nh) * is;       // == w*y (0 where masked, y=0 there)
            pV[p] = (swv[p] * nv) * is;
            if (a) { *(h4*)&sPH[bF] = pH[p]; *(h4*)&sPV[bF] = pV[p]; }
        }
    };

    // ---- primal: x = (x + tau*div(p) + lt*img)/(1+lt); xt = 1.5x - 0.5xo ----
    auto primal = [&]() {
        #pragma unroll
        for (int p = 0; p < NPASS; ++p) {
            bool a = act_[p]; int u = u_[p], bF = bF_[p];
            int bu = (u >= UPR) ? bF - PC : bF;          // up unit (clamped)
            h4 pvu = a ? *(const h4*)&sPV[bu] : h4splat(0.f);
            float ph3 = (float)pH[p][3];
            float phl = __shfl_up(ph3, 1, 64);
            if (lane == 0 && a && u > 0) phl = (float)sPH[bF - 1];
            bool iok = gi_[p] >= 1;
            float xtv[4];
            #pragma unroll
            for (int l = 0; l < 4; ++l) {
                float p_h  = (float)pH[p][l];
                float p_hm = (l == 0) ? phl : (float)pH[p][l - 1];
                if (gjb_[p] + l < 1) p_hm = 0.f;         // image left edge
                float p_v  = (float)pV[p][l];
                float p_vm = iok ? (float)pvu[l] : 0.f;  // image top edge
                float dvg  = (p_h - p_hm) + (p_v - p_vm);
                float xo = xr[p][l];
                float xn = (fmaf(TAU, dvg, xo) + LT * xi[p][l]) * INV_DEN;
                xr[p][l] = xn;
                float v = fmaf(1.5f, xn, -0.5f * xo);    // THETA = 0.5
                xt[p][l] = v; xtv[l] = v;
            }
            if (a) *(float4*)&sXT[bF] = make_float4(xtv[0], xtv[1], xtv[2], xtv[3]);
        }
    };

    primal();                 // t=0 (dual(0) fused into init)
    __syncthreads();
    #pragma unroll 1
    for (int t = 1; t < 10; ++t) {
        dual();
        __syncthreads();
        primal();
        __syncthreads();
    }

    // ---- output xt(9): rows 10..73, cols 12..75 ----
    {
        int row = tid >> 4;          // 0..63
        int cu  = tid & 15;          // 0..15
        int li = 10 + row, lj = 12 + 4 * cu;
        float4 v = *(const float4*)&sXT[li * PC + lj];
        *(float4*)&out[(size_t)(r0 + row) * N + (c0 + 4 * cu)] = v;
    }
}

extern "C" void kernel_launch(void* const* d_in, const int* in_sizes, int n_in,
                              void* d_out, int out_size, void* d_ws, size_t ws_size,
                              hipStream_t stream)
{
    const float* img = (const float*)d_in[0];
    const float* w1  = (const float*)d_in[1];
    const float* w2  = (const float*)d_in[2];
    float* out = (float*)d_out;

    dim3 grid(N / TW, M / TH);   // 32 x 32 = 1024 blocks
    pd_fused<<<grid, NT, 0, stream>>>(img, out, w1, w2);
}